// Round 10
// baseline (154.760 us; speedup 1.0000x reference)
//
#include <hip/hip_runtime.h>

typedef __attribute__((ext_vector_type(8))) short bf16x8;
typedef __attribute__((ext_vector_type(4))) float f32x4;
typedef __attribute__((ext_vector_type(4))) float fvec4;

__device__ __forceinline__ unsigned short f2bf(float x) {
    unsigned int u = __float_as_uint(x);
    u += 0x7FFFu + ((u >> 16) & 1u);        // round-to-nearest-even
    return (unsigned short)(u >> 16);
}

// async global->LDS, 16B per lane; LDS dest = wave-uniform base + lane*16.
__device__ __forceinline__ void gl_lds16(const void* g, void* l) {
    __builtin_amdgcn_global_load_lds(
        (__attribute__((address_space(1))) void*)((void*)g),
        (__attribute__((address_space(3))) void*)l, 16, 0, 0);
}

#define SFENCE __builtin_amdgcn_sched_barrier(0)

// ---------------------------------------------------------------------------
// prep: WbT[n][k] = bf16(W[k][n]) via coalesced 32x32 LDS transpose. Grid 64.
// ---------------------------------------------------------------------------
__global__ __launch_bounds__(256) void prep(const float* __restrict__ W,
                                            short* __restrict__ WbT) {
    __shared__ float tile[32][33];
    const int t = threadIdx.x;
    const int bx = blockIdx.x & 7, by = blockIdx.x >> 3;
    const int r0 = by * 32, c0 = bx * 32;
    const int lr = t >> 5, lc = t & 31;
#pragma unroll
    for (int q = 0; q < 4; ++q)
        tile[q * 8 + lr][lc] = W[(r0 + q * 8 + lr) * 256 + c0 + lc];
    __syncthreads();
#pragma unroll
    for (int q = 0; q < 4; ++q)
        WbT[(c0 + q * 8 + lr) * 256 + r0 + lc] = (short)f2bf(tile[lc][q * 8 + lr]);
}

// ---------------------------------------------------------------------------
// setup2: heterogeneous grid 4608. Blocks 0..511 run the wh_f12 role
// (compute-bound); blocks 512..4607 run the bitpack role (pure HBM stream).
// WhT stored TILE-MAJOR: WhT[b][T][f][64], T = j>>6 -- each (b,T) tile is a
// dense 32 KB block; fused_agg waves stage contiguous 8 KB row-bands of it.
// ---------------------------------------------------------------------------
__global__ __launch_bounds__(256, 4) void setup2(const float* __restrict__ h,
                                                 const short* __restrict__ WbT,
                                                 const float* __restrict__ a,
                                                 const int* __restrict__ adj,
                                                 short* __restrict__ WhT,
                                                 float* __restrict__ f1,
                                                 float* __restrict__ f2,
                                                 unsigned long long* __restrict__ bits) {
    __shared__ short hA[32][264];      // +8 pad -> 2-way bank aliasing (free)
    __shared__ float sp[2][4][32];
    const int t = threadIdx.x;
    const int wid = t >> 6, lane = t & 63;

    if (blockIdx.x >= 512) {
        // ---- bitpack role: wave per row, __ballot per 64 cols; lanes 0..15
        //      store the row's 16 words (128 B contiguous).
        const int row = (blockIdx.x - 512) * 4 + wid;        // 0..16383
        const int* arow = adj + (size_t)row * 1024;
        unsigned long long myword = 0ull;
#pragma unroll
        for (int w = 0; w < 16; ++w) {
            int v = __builtin_nontemporal_load(arow + w * 64 + lane);
            unsigned long long bal = __ballot(v != 0);
            if (lane == w) myword = bal;
        }
        if (lane < 16) bits[(size_t)row * 16 + lane] = myword;
        return;
    }

    // ---- wh_f12 role: 32 nodes/block; WhT bf16 tile-major; f1/f2 fused.
    const int quad = lane >> 4, l15 = lane & 15;
    const int m0 = blockIdx.x * 32;

    // stage h-tile (2 rows per 16-thread group; 64 B contiguous/thread)
#pragma unroll
    for (int rr = 0; rr < 2; ++rr) {
        const int r = rr * 16 + (t >> 4), c0 = (t & 15) * 16;
        const float* hp = h + (size_t)(m0 + r) * 256 + c0;
        fvec4 v0 = __builtin_nontemporal_load((const fvec4*)(hp + 0));
        fvec4 v1 = __builtin_nontemporal_load((const fvec4*)(hp + 4));
        fvec4 v2 = __builtin_nontemporal_load((const fvec4*)(hp + 8));
        fvec4 v3 = __builtin_nontemporal_load((const fvec4*)(hp + 12));
        bf16x8 w0, w1;
#pragma unroll
        for (int u = 0; u < 4; ++u) {
            w0[u]     = (short)f2bf(v0[u]);
            w0[u + 4] = (short)f2bf(v1[u]);
            w1[u]     = (short)f2bf(v2[u]);
            w1[u + 4] = (short)f2bf(v3[u]);
        }
        *(bf16x8*)&hA[r][c0] = w0;
        *(bf16x8*)&hA[r][c0 + 8] = w1;
    }
    __syncthreads();

    f32x4 acc[2][4] = {};
#pragma unroll
    for (int kt = 0; kt < 8; ++kt) {
        const int k0 = kt * 32;
        bf16x8 bv[4];
#pragma unroll
        for (int ft = 0; ft < 4; ++ft)
            bv[ft] = *(const bf16x8*)(WbT + (size_t)(wid * 64 + ft * 16 + l15) * 256 + k0 + quad * 8);
        bf16x8 a0 = *(const bf16x8*)&hA[l15][k0 + quad * 8];
        bf16x8 a1 = *(const bf16x8*)&hA[16 + l15][k0 + quad * 8];
#pragma unroll
        for (int ft = 0; ft < 4; ++ft) {
            acc[0][ft] = __builtin_amdgcn_mfma_f32_16x16x32_bf16(a0, bv[ft], acc[0][ft], 0, 0, 0);
            acc[1][ft] = __builtin_amdgcn_mfma_f32_16x16x32_bf16(a1, bv[ft], acc[1][ft], 0, 0, 0);
        }
    }

    // WhT store, tile-major: addr = (b<<18) + (j>>6)*16384 + f*64 + (j&63)
    const int b = m0 >> 10;
#pragma unroll
    for (int mf = 0; mf < 2; ++mf) {
        const int il0 = (m0 & 1023) + mf * 16 + quad * 4;   // j index (mult of 4)
        const int T = il0 >> 6, jw = il0 & 63;
#pragma unroll
        for (int ft = 0; ft < 4; ++ft) {
            const int f = wid * 64 + ft * 16 + l15;
            ushort4 pk;
            pk.x = f2bf(acc[mf][ft][0]);
            pk.y = f2bf(acc[mf][ft][1]);
            pk.z = f2bf(acc[mf][ft][2]);
            pk.w = f2bf(acc[mf][ft][3]);
            *(ushort4*)(WhT + ((size_t)b << 18) + T * 16384 + (size_t)f * 64 + jw) = pk;
        }
    }

    // f1/f2 from fp32 acc: dot with a1/a2 over this wave's 64-f slice
    float a1v[4], a2v[4];
#pragma unroll
    for (int ft = 0; ft < 4; ++ft) {
        a1v[ft] = a[wid * 64 + ft * 16 + l15];
        a2v[ft] = a[256 + wid * 64 + ft * 16 + l15];
    }
    float p1[2][4] = {}, p2[2][4] = {};
#pragma unroll
    for (int mf = 0; mf < 2; ++mf)
#pragma unroll
        for (int ft = 0; ft < 4; ++ft)
#pragma unroll
            for (int r = 0; r < 4; ++r) {
                p1[mf][r] += acc[mf][ft][r] * a1v[ft];
                p2[mf][r] += acc[mf][ft][r] * a2v[ft];
            }
#pragma unroll
    for (int off = 1; off < 16; off <<= 1)
#pragma unroll
        for (int mf = 0; mf < 2; ++mf)
#pragma unroll
            for (int r = 0; r < 4; ++r) {
                p1[mf][r] += __shfl_xor(p1[mf][r], off);
                p2[mf][r] += __shfl_xor(p2[mf][r], off);
            }
    if (l15 == 0)
#pragma unroll
        for (int mf = 0; mf < 2; ++mf)
#pragma unroll
            for (int r = 0; r < 4; ++r) {
                sp[0][wid][mf * 16 + quad * 4 + r] = p1[mf][r];
                sp[1][wid][mf * 16 + quad * 4 + r] = p2[mf][r];
            }
    __syncthreads();
    if (t < 32) {
        f1[m0 + t] = sp[0][0][t] + sp[0][1][t] + sp[0][2][t] + sp[0][3][t];
        f2[m0 + t] = sp[1][0][t] + sp[1][1][t] + sp[1][2][t] + sp[1][3][t];
    }
}

// ---------------------------------------------------------------------------
// fused_agg v10: BARRIER-FREE k-loop (round-9 diagnosis: per-tile lockstep
// barriers at 2 waves/SIMD were the unexplained ~20 us; all pipes <16%).
// BM=64, BN=256, grid 256 (1 block/CU), 512 thr = 8 waves (2M x 4N), wave
// tile 32m x 64n.
// - B: WAVE-PRIVATE gl_lds staging: each wave stages only its 64 n-rows
//   (8 KB/tile, contiguous band of the tile-major WhT) into a private
//   2-deep ring. Producer == consumer -> per-wave counted vmcnt, NO
//   barriers. 16 KB in flight/wave. (wm-pair duplicates staging 2x --
//   ~7 us L2-BW floor, far below the 26 us barrier cost it removes.)
// - P: IN REGISTERS. Each lane computes exactly its own MFMA A-fragments
//   (2 rows x 16 k per tile) from LDS-resident bits/f2 (read-only after the
//   single prologue barrier). 4x redundant exp across wn waves -- pure
//   VALU/TRANS, overlapped, no sync.
// - Row sums in registers; quad-slice shfl_xor reduce + per-row shfl at end.
// Exactly ONE __syncthreads in the whole kernel.
// ---------------------------------------------------------------------------
__global__ __launch_bounds__(512) void fused_agg(const unsigned long long* __restrict__ bitsG,
                                                 const float* __restrict__ f1g,
                                                 const float* __restrict__ f2g,
                                                 const short* __restrict__ WhT,
                                                 float* __restrict__ out) {
    __shared__ short Bs[8][2][4096];              // 128 KB: wave-private 2-deep ring
    __shared__ unsigned long long bitsS[16 * 64]; // 8 KB, [word][row]
    __shared__ float f2s[1024];                   // 4 KB

    const int t = threadIdx.x;
    const int wid = t >> 6, lane = t & 63;
    const int quad = lane >> 4, l15 = lane & 15;
    const int wm = wid >> 2, wn = wid & 3;
    const int mh = wm * 32, nq = wn * 64;

    // XCD-aware decode: xcd = id&7, b = xcd + 8*(rest&1), m-tile = rest>>1
    const int id = blockIdx.x;
    const int xcd = id & 7, rest = id >> 3;
    const int b = xcd + 8 * (rest & 1);
    const int m0 = (rest >> 1) * 64;

    const short* Wb = WhT + ((size_t)b << 18);    // tile-major [T][f][64]

    // ---- prologue: bits (transposed [word][row]) + f2 to LDS; f1 to regs
    {
        const unsigned long long* bsrc = bitsG + (size_t)((b << 10) + m0) * 16;
        ulonglong2 bv2 = ((const ulonglong2*)bsrc)[t];    // words 2t, 2t+1
        const int g0 = 2 * t, g1 = 2 * t + 1;
        bitsS[(g0 & 15) * 64 + (g0 >> 4)] = bv2.x;
        bitsS[(g1 & 15) * 64 + (g1 >> 4)] = bv2.y;
        ((float2*)f2s)[t] = ((const float2*)(f2g + (b << 10)))[t];
    }
    const float f1a = f1g[(b << 10) + m0 + mh + l15];        // row mh+l15
    const float f1b = f1g[(b << 10) + m0 + mh + 16 + l15];   // row mh+16+l15
    __syncthreads();   // the ONLY barrier: bits/f2 visible; vmcnt drained to 0

    short* bufA = &Bs[wid][0][0];
    short* bufB = &Bs[wid][1][0];

    // wave-private stage: 8 gl_lds16 covering this wave's 64 rows (8 KB);
    // global slot (c&7)^(rr&7) pre-applies the read-side involution.
    auto stageTo = [&](int T, short* dst) {
        const short* src = Wb + (size_t)T * 16384 + (size_t)nq * 64;
#pragma unroll
        for (int j = 0; j < 8; ++j) {
            const int c = j * 64 + lane;
            const int rr = c >> 3, sl = (c & 7) ^ (rr & 7);
            gl_lds16(src + rr * 64 + sl * 8, dst + c * 8);
        }
    };

    f32x4 acc[2][4] = {};
    float ls0 = 0.f, ls1 = 0.f;

    stageTo(0, bufA);     // 8 outstanding
    stageTo(1, bufB);     // 16 outstanding

    // per-tile body. Precondition: tile T landed in bufRead (vmcnt waited).
    auto body = [&](int T, short* bufRead, bool doStage) {
        // B fragments of tile T -> registers
        bf16x8 bv[2][4];
#pragma unroll
        for (int kt = 0; kt < 2; ++kt)
#pragma unroll
            for (int nf = 0; nf < 4; ++nf) {
                const int rb = nf * 16 + l15;
                const int w = kt * 4 + quad;
                bv[kt][nf] = *(const bf16x8*)(bufRead + rb * 64 + ((w ^ (rb & 7)) * 8));
            }
        asm volatile("s_waitcnt lgkmcnt(0)" ::: "memory");  // B in regs
        SFENCE;
        if (doStage) stageTo(T + 2, bufRead);               // safe to overwrite now

        // P fragments of tile T -> registers (lane's own A-frags)
        const unsigned long long w0 = bitsS[T * 64 + mh + l15];
        const unsigned long long w1 = bitsS[T * 64 + mh + 16 + l15];
        bf16x8 pa[2][2];
#pragma unroll
        for (int kt = 0; kt < 2; ++kt) {
            const float* fp = f2s + T * 64 + kt * 32 + quad * 8;
            float4 fa = *(const float4*)fp;
            float4 fb = *(const float4*)(fp + 4);
            float xv[8] = {fa.x, fa.y, fa.z, fa.w, fb.x, fb.y, fb.z, fb.w};
            const int sh = kt * 32 + quad * 8;
            const unsigned int m80 = (unsigned int)(w0 >> sh) & 0xffu;
            const unsigned int m81 = (unsigned int)(w1 >> sh) & 0xffu;
#pragma unroll
            for (int u = 0; u < 8; ++u) {
                float x0 = f1a + xv[u];
                x0 = fmaxf(x0, 0.2f * x0);                       // leaky relu
                float p0 = ((m80 >> u) & 1u) ? __expf(x0) : 0.f; // unnorm, m=0
                ls0 += p0;
                pa[0][kt][u] = (short)f2bf(p0);
                float x1 = f1b + xv[u];
                x1 = fmaxf(x1, 0.2f * x1);
                float p1 = ((m81 >> u) & 1u) ? __expf(x1) : 0.f;
                ls1 += p1;
                pa[1][kt][u] = (short)f2bf(p1);
            }
        }

        __builtin_amdgcn_s_setprio(1);
#pragma unroll
        for (int kt = 0; kt < 2; ++kt)
#pragma unroll
            for (int mf = 0; mf < 2; ++mf)
#pragma unroll
                for (int nf = 0; nf < 4; ++nf)
                    acc[mf][nf] = __builtin_amdgcn_mfma_f32_16x16x32_bf16(
                        mf ? pa[1][kt] : pa[0][kt], bv[kt][nf], acc[mf][nf], 0, 0, 0);
        __builtin_amdgcn_s_setprio(0);
    };

    // ---- barrier-free main loop: invariant 16 outstanding (tiles T, T+1);
    //      vmcnt(8) retires tile T; stage(T+2) restores 16.
    for (int Tp = 0; Tp < 7; ++Tp) {
        const int T0 = Tp * 2;
        asm volatile("s_waitcnt vmcnt(8)" ::: "memory");   // tile T0 landed
        SFENCE;
        body(T0, bufA, true);
        asm volatile("s_waitcnt vmcnt(8)" ::: "memory");   // tile T0+1 landed
        SFENCE;
        body(T0 + 1, bufB, true);
    }
    asm volatile("s_waitcnt vmcnt(8)" ::: "memory");
    SFENCE;
    body(14, bufA, false);
    asm volatile("s_waitcnt vmcnt(0)" ::: "memory");
    SFENCE;
    body(15, bufB, false);

    // ---- row sums: reduce the quad k-slices (lanes differ in bits 4-5)
    ls0 += __shfl_xor(ls0, 16); ls0 += __shfl_xor(ls0, 32);
    ls1 += __shfl_xor(ls1, 16); ls1 += __shfl_xor(ls1, 32);

    // ---- epilogue: C row = mh + mf*16 + quad*4 + r, col = nq + nf*16 + l15;
    //      row (quad*4+r)'s sum lives in lane l15 = quad*4+r (any quad).
#pragma unroll
    for (int mf = 0; mf < 2; ++mf) {
        const int il = mh + mf * 16 + quad * 4;
#pragma unroll
        for (int r = 0; r < 4; ++r) {
            const float s = __shfl(mf ? ls1 : ls0, quad * 4 + r);
            const float inv = 1.0f / s;
            float* op = out + (size_t)((b << 10) + m0 + il + r) * 256 + nq + l15;
#pragma unroll
            for (int nf = 0; nf < 4; ++nf)
                op[nf * 16] = acc[mf][nf][r] * inv;
        }
    }
}

// ---------------------------------------------------------------------------
extern "C" void kernel_launch(void* const* d_in, const int* in_sizes, int n_in,
                              void* d_out, int out_size, void* d_ws, size_t ws_size,
                              hipStream_t stream) {
    const float* h   = (const float*)d_in[0];
    const int*   adj = (const int*)d_in[1];
    const float* W   = (const float*)d_in[2];
    const float* a   = (const float*)d_in[3];
    float* out = (float*)d_out;

    short* WbT = (short*)d_ws;                       // 128 KB
    float* f1  = (float*)(WbT + 65536);              // 64 KB
    float* f2  = f1 + 16384;                         // 64 KB
    short* WhT = (short*)(f2 + 16384);               // 8 MB (tile-major)
    unsigned long long* bits =
        (unsigned long long*)(WhT + 16 * 256 * 1024);// 2 MB

    prep<<<64, 256, 0, stream>>>(W, WbT);
    setup2<<<4608, 256, 0, stream>>>(h, WbT, a, adj, WhT, f1, f2, bits);
    fused_agg<<<256, 512, 0, stream>>>(bits, f1, f2, WhT, out);
}

// Round 11
// 136.419 us; speedup vs baseline: 1.1344x; 1.1344x over previous
//
#include <hip/hip_runtime.h>

typedef __attribute__((ext_vector_type(8))) short bf16x8;
typedef __attribute__((ext_vector_type(4))) float f32x4;

__device__ __forceinline__ unsigned short f2bf(float x) {
    unsigned int u = __float_as_uint(x);
    u += 0x7FFFu + ((u >> 16) & 1u);        // round-to-nearest-even
    return (unsigned short)(u >> 16);
}

// async global->LDS, 16B per lane; LDS dest = wave-uniform base + lane*16.
__device__ __forceinline__ void gl_lds16(const void* g, void* l) {
    __builtin_amdgcn_global_load_lds(
        (__attribute__((address_space(1))) void*)((void*)g),
        (__attribute__((address_space(3))) void*)l, 16, 0, 0);
}

#define SFENCE __builtin_amdgcn_sched_barrier(0)

// ---------------------------------------------------------------------------
// prep: WbT[n][k] = bf16(W[k][n]) via coalesced 32x32 LDS transpose. Grid 64.
// ---------------------------------------------------------------------------
__global__ __launch_bounds__(256) void prep(const float* __restrict__ W,
                                            short* __restrict__ WbT) {
    __shared__ float tile[32][33];
    const int t = threadIdx.x;
    const int bx = blockIdx.x & 7, by = blockIdx.x >> 3;
    const int r0 = by * 32, c0 = bx * 32;
    const int lr = t >> 5, lc = t & 31;
#pragma unroll
    for (int q = 0; q < 4; ++q)
        tile[q * 8 + lr][lc] = W[(r0 + q * 8 + lr) * 256 + c0 + lc];
    __syncthreads();
#pragma unroll
    for (int q = 0; q < 4; ++q)
        WbT[(c0 + q * 8 + lr) * 256 + r0 + lc] = (short)f2bf(tile[lc][q * 8 + lr]);
}

// ---------------------------------------------------------------------------
// setup2: heterogeneous grid 4608. Blocks 0..511 run the wh_f12 role
// (compute-bound: MFMA + LDS); blocks 512..4607 run the bitpack role
// (pure HBM stream, 64 MB read). No data dependence between roles -> they
// co-schedule and wh_f12's ~4-5 us hides under bitpack's ~10.5 us stream.
// ---------------------------------------------------------------------------
__global__ __launch_bounds__(256, 4) void setup2(const float* __restrict__ h,
                                                 const short* __restrict__ WbT,
                                                 const float* __restrict__ a,
                                                 const int* __restrict__ adj,
                                                 short* __restrict__ WhT,
                                                 float* __restrict__ f1,
                                                 float* __restrict__ f2,
                                                 unsigned long long* __restrict__ bits) {
    __shared__ short hA[32][264];      // +8 pad -> 2-way bank aliasing (free)
    __shared__ float sp[2][4][32];
    const int t = threadIdx.x;
    const int wid = t >> 6, lane = t & 63;

    if (blockIdx.x >= 512) {
        // ---- bitpack role: wave per row, __ballot per 64 cols; lanes 0..15
        //      store the row's 16 words (128 B contiguous).
        const int row = (blockIdx.x - 512) * 4 + wid;        // 0..16383
        const int* arow = adj + (size_t)row * 1024;
        unsigned long long myword = 0ull;
#pragma unroll
        for (int w = 0; w < 16; ++w) {
            int v = arow[w * 64 + lane];
            unsigned long long bal = __ballot(v != 0);
            if (lane == w) myword = bal;
        }
        if (lane < 16) bits[(size_t)row * 16 + lane] = myword;
        return;
    }

    // ---- wh_f12 role: 32 nodes/block; WhT bf16-transposed; f1/f2 fused.
    const int quad = lane >> 4, l15 = lane & 15;
    const int m0 = blockIdx.x * 32;

    // stage h-tile (2 rows per 16-thread group; 64 B contiguous/thread)
#pragma unroll
    for (int rr = 0; rr < 2; ++rr) {
        const int r = rr * 16 + (t >> 4), c0 = (t & 15) * 16;
        const float* hp = h + (size_t)(m0 + r) * 256 + c0;
        float4 v0 = *(const float4*)(hp + 0), v1 = *(const float4*)(hp + 4);
        float4 v2 = *(const float4*)(hp + 8), v3 = *(const float4*)(hp + 12);
        bf16x8 w0, w1;
        w0[0] = (short)f2bf(v0.x); w0[1] = (short)f2bf(v0.y);
        w0[2] = (short)f2bf(v0.z); w0[3] = (short)f2bf(v0.w);
        w0[4] = (short)f2bf(v1.x); w0[5] = (short)f2bf(v1.y);
        w0[6] = (short)f2bf(v1.z); w0[7] = (short)f2bf(v1.w);
        w1[0] = (short)f2bf(v2.x); w1[1] = (short)f2bf(v2.y);
        w1[2] = (short)f2bf(v2.z); w1[3] = (short)f2bf(v2.w);
        w1[4] = (short)f2bf(v3.x); w1[5] = (short)f2bf(v3.y);
        w1[6] = (short)f2bf(v3.z); w1[7] = (short)f2bf(v3.w);
        *(bf16x8*)&hA[r][c0] = w0;
        *(bf16x8*)&hA[r][c0 + 8] = w1;
    }
    __syncthreads();

    f32x4 acc[2][4] = {};
#pragma unroll
    for (int kt = 0; kt < 8; ++kt) {
        const int k0 = kt * 32;
        bf16x8 bv[4];
#pragma unroll
        for (int ft = 0; ft < 4; ++ft)
            bv[ft] = *(const bf16x8*)(WbT + (size_t)(wid * 64 + ft * 16 + l15) * 256 + k0 + quad * 8);
        bf16x8 a0 = *(const bf16x8*)&hA[l15][k0 + quad * 8];
        bf16x8 a1 = *(const bf16x8*)&hA[16 + l15][k0 + quad * 8];
#pragma unroll
        for (int ft = 0; ft < 4; ++ft) {
            acc[0][ft] = __builtin_amdgcn_mfma_f32_16x16x32_bf16(a0, bv[ft], acc[0][ft], 0, 0, 0);
            acc[1][ft] = __builtin_amdgcn_mfma_f32_16x16x32_bf16(a1, bv[ft], acc[1][ft], 0, 0, 0);
        }
    }

    // WhT store (C row = quad*4+reg, col f = wid*64+ft*16+l15)
    const int b = m0 >> 10;
#pragma unroll
    for (int mf = 0; mf < 2; ++mf) {
        const int il0 = (m0 & 1023) + mf * 16 + quad * 4;
#pragma unroll
        for (int ft = 0; ft < 4; ++ft) {
            const int f = wid * 64 + ft * 16 + l15;
            ushort4 pk;
            pk.x = f2bf(acc[mf][ft][0]);
            pk.y = f2bf(acc[mf][ft][1]);
            pk.z = f2bf(acc[mf][ft][2]);
            pk.w = f2bf(acc[mf][ft][3]);
            *(ushort4*)(WhT + ((size_t)b << 18) + (size_t)f * 1024 + il0) = pk;
        }
    }

    // f1/f2 from fp32 acc: dot with a1/a2 over this wave's 64-f slice
    float a1v[4], a2v[4];
#pragma unroll
    for (int ft = 0; ft < 4; ++ft) {
        a1v[ft] = a[wid * 64 + ft * 16 + l15];
        a2v[ft] = a[256 + wid * 64 + ft * 16 + l15];
    }
    float p1[2][4] = {}, p2[2][4] = {};
#pragma unroll
    for (int mf = 0; mf < 2; ++mf)
#pragma unroll
        for (int ft = 0; ft < 4; ++ft)
#pragma unroll
            for (int r = 0; r < 4; ++r) {
                p1[mf][r] += acc[mf][ft][r] * a1v[ft];
                p2[mf][r] += acc[mf][ft][r] * a2v[ft];
            }
#pragma unroll
    for (int off = 1; off < 16; off <<= 1)
#pragma unroll
        for (int mf = 0; mf < 2; ++mf)
#pragma unroll
            for (int r = 0; r < 4; ++r) {
                p1[mf][r] += __shfl_xor(p1[mf][r], off);
                p2[mf][r] += __shfl_xor(p2[mf][r], off);
            }
    if (l15 == 0)
#pragma unroll
        for (int mf = 0; mf < 2; ++mf)
#pragma unroll
            for (int r = 0; r < 4; ++r) {
                sp[0][wid][mf * 16 + quad * 4 + r] = p1[mf][r];
                sp[1][wid][mf * 16 + quad * 4 + r] = p2[mf][r];
            }
    __syncthreads();
    if (t < 32) {
        f1[m0 + t] = sp[0][0][t] + sp[0][1][t] + sp[0][2][t] + sp[0][3][t];
        f2[m0 + t] = sp[1][0][t] + sp[1][1][t] + sp[1][2][t] + sp[1][3][t];
    }
}

// ---------------------------------------------------------------------------
// fused_agg v7 (best measured, 137.9 us total): counted-vmcnt pipeline, ONE
// s_barrier per k-tile + s_setprio around the MFMA cluster. BM=64, BN=256,
// BK=64, grid 256 (1 block/CU), 512 thr = 8 waves (2M x 4N), wave tile
// 32m x 64n. Loop invariants at each barrier: tile T landed in Bs[T%3]
// (prev iter's per-wave vmcnt(4) THEN barrier = cross-wave guarantee),
// Ps[T&1] holds P(T) (lgkmcnt(0) before the barrier), and all waves finished
// reading Bs[(T-1)%3] / Ps[(T-1)&1] -- so stage(T+2)/pgen(T+1) may overwrite
// those buffers immediately after the barrier. vmcnt never drains mid-loop.
// [r8: 2-blocks/CU regressed; r9: tile-major staging regressed; r10:
//  barrier-free wave-private regressed -- this structure is the measured
//  local optimum.]
// ---------------------------------------------------------------------------
__global__ __launch_bounds__(512, 2) void fused_agg(const unsigned long long* __restrict__ bitsG,
                                                    const float* __restrict__ f1g,
                                                    const float* __restrict__ f2g,
                                                    const short* __restrict__ WhT,
                                                    float* __restrict__ out) {
    __shared__ short Bs[3][256 * 64];             // 96 KB ring, swizzled rows
    __shared__ short Ps[2][64 * 64];              // 16 KB dbuf, swizzled rows
    __shared__ unsigned long long bitsS[16 * 64]; // 8 KB, [word][row] (transposed)
    __shared__ float f2s[1024];                   // 4 KB
    __shared__ float lred[512];
    __shared__ float linv[64];

    const int t = threadIdx.x;
    const int wid = t >> 6, lane = t & 63;
    const int quad = lane >> 4, l15 = lane & 15;

    // XCD-aware decode: xcd = id&7, b = xcd + 8*(rest&1), m-tile = rest>>1
    const int id = blockIdx.x;
    const int xcd = id & 7, rest = id >> 3;
    const int b = xcd + 8 * (rest & 1);
    const int m0 = (rest >> 1) * 64;

    const short* Wb = WhT + ((size_t)b << 18);

    // ---- prologue: bits (transposed [word][row]) + f2 + f1 resident
    {
        const unsigned long long* bsrc = bitsG + (size_t)((b << 10) + m0) * 16;
        ulonglong2 bv = ((const ulonglong2*)bsrc)[t];     // words 2t, 2t+1
        const int g0 = 2 * t, g1 = 2 * t + 1;
        bitsS[(g0 & 15) * 64 + (g0 >> 4)] = bv.x;
        bitsS[(g1 & 15) * 64 + (g1 >> 4)] = bv.y;
        ((float2*)f2s)[t] = ((const float2*)(f2g + (b << 10)))[t];
    }
    const int pr = t >> 3, ps = t & 7;            // P-gen role: row, chunk
    const float f1r = f1g[(b << 10) + m0 + pr];
    __syncthreads();                              // drains all prologue vmem

    // ---- staging: chunk c = t + 512q -> LDS byte c*16 (linear per wave);
    //      global slot = (c&7) ^ (row&7), row = c>>3 (the read-side involution)
    auto stage = [&](int T, short* buf) {
#pragma unroll
        for (int q = 0; q < 4; ++q) {
            const int c = t + 512 * q;
            const int rr = c >> 3;
            const int sl = (c & 7) ^ (rr & 7);
            gl_lds16(Wb + (size_t)rr * 1024 + T * 64 + sl * 8, buf + c * 8);
        }
    };

    float lacc = 0.f;
    auto pgen = [&](int T, short* pbuf) {
        unsigned int m8 = (unsigned int)(bitsS[T * 64 + pr] >> (ps * 8)) & 0xffu;
        float4 fa = *(const float4*)(f2s + T * 64 + ps * 8);
        float4 fb = *(const float4*)(f2s + T * 64 + ps * 8 + 4);
        float xv[8] = {fa.x, fa.y, fa.z, fa.w, fb.x, fb.y, fb.z, fb.w};
        bf16x8 pw;
#pragma unroll
        for (int u = 0; u < 8; ++u) {
            float x = f1r + xv[u];
            x = fmaxf(x, 0.2f * x);                       // leaky relu
            float pv = ((m8 >> u) & 1u) ? __expf(x) : 0.f; // unnorm, m=0 (e<=~6.5)
            lacc += pv;
            pw[u] = (short)f2bf(pv);
        }
        *(bf16x8*)(pbuf + pr * 64 + ((ps ^ (pr & 7)) * 8)) = pw;
    };

    const int wm = wid >> 2, wn = wid & 3;
    const int mh = wm * 32, nq = wn * 64;
    f32x4 acc[2][4] = {};

    auto step = [&](const short* pbuf, const short* bbuf) {
#pragma unroll
        for (int kt = 0; kt < 2; ++kt) {
            const int w = kt * 4 + quad;
            bf16x8 av[2], bv[4];
#pragma unroll
            for (int mf = 0; mf < 2; ++mf) {
                const int ra = mh + mf * 16 + l15;
                av[mf] = *(const bf16x8*)(pbuf + ra * 64 + ((w ^ (ra & 7)) * 8));
            }
#pragma unroll
            for (int nf = 0; nf < 4; ++nf) {
                const int rb = nq + nf * 16 + l15;
                bv[nf] = *(const bf16x8*)(bbuf + rb * 64 + ((w ^ (rb & 7)) * 8));
            }
#pragma unroll
            for (int mf = 0; mf < 2; ++mf)
#pragma unroll
                for (int nf = 0; nf < 4; ++nf)
                    acc[mf][nf] = __builtin_amdgcn_mfma_f32_16x16x32_bf16(av[mf], bv[nf], acc[mf][nf], 0, 0, 0);
        }
    };

    // ---- pipeline prologue: tiles 0,1 in flight; P(0) built
    stage(0, Bs[0]);
    stage(1, Bs[1]);
    pgen(0, Ps[0]);
    asm volatile("s_waitcnt lgkmcnt(0)" ::: "memory");
    SFENCE;
    asm volatile("s_waitcnt vmcnt(4)" ::: "memory");   // tile 0 landed, 1 in flight
    SFENCE;
    __builtin_amdgcn_s_barrier();
    SFENCE;

    // ---- main loop: 16 k-tiles, ONE barrier per tile, counted vmcnt
#pragma unroll
    for (int T = 0; T < 16; ++T) {
        if (T < 14) stage(T + 2, Bs[(T + 2) % 3]);     // overwrites Bs[(T-1)%3]
        if (T < 15) pgen(T + 1, Ps[(T + 1) & 1]);      // overwrites Ps[(T-1)&1]
        __builtin_amdgcn_s_setprio(1);
        step(Ps[T & 1], Bs[T % 3]);
        __builtin_amdgcn_s_setprio(0);
        asm volatile("s_waitcnt lgkmcnt(0)" ::: "memory");  // P(T+1) writes drained
        SFENCE;
        if (T < 14) {
            asm volatile("s_waitcnt vmcnt(4)" ::: "memory");  // tile T+1 landed (own wave)
        } else if (T == 14) {
            asm volatile("s_waitcnt vmcnt(0)" ::: "memory");  // tile 15: pipeline drain
        }
        SFENCE;
        __builtin_amdgcn_s_barrier();   // cross-wave: tile T+1 + P(T+1) visible;
        SFENCE;                         // all reads of Bs[T%3]/Ps[T&1] complete
    }

    // ---- row-sum reduce: 8 partials per row (lred[r*8+sub]) -> 1/l
    lred[t] = lacc;
    __syncthreads();
    if (t < 64) {
        const float* lp = lred + t * 8;
        linv[t] = 1.0f / (((lp[0] + lp[1]) + (lp[2] + lp[3])) +
                          ((lp[4] + lp[5]) + (lp[6] + lp[7])));
    }
    __syncthreads();

    // ---- epilogue: C row = mh + mf*16 + quad*4 + reg, col = nq + nf*16 + l15
#pragma unroll
    for (int mf = 0; mf < 2; ++mf) {
        const int il = mh + mf * 16 + quad * 4;
        const float i0 = linv[il], i1 = linv[il + 1];
        const float i2 = linv[il + 2], i3 = linv[il + 3];
#pragma unroll
        for (int nf = 0; nf < 4; ++nf) {
            float* op = out + (size_t)((b << 10) + m0 + il) * 256 + nq + nf * 16 + l15;
            op[0]   = acc[mf][nf][0] * i0;
            op[256] = acc[mf][nf][1] * i1;
            op[512] = acc[mf][nf][2] * i2;
            op[768] = acc[mf][nf][3] * i3;
        }
    }
}

// ---------------------------------------------------------------------------
extern "C" void kernel_launch(void* const* d_in, const int* in_sizes, int n_in,
                              void* d_out, int out_size, void* d_ws, size_t ws_size,
                              hipStream_t stream) {
    const float* h   = (const float*)d_in[0];
    const int*   adj = (const int*)d_in[1];
    const float* W   = (const float*)d_in[2];
    const float* a   = (const float*)d_in[3];
    float* out = (float*)d_out;

    short* WbT = (short*)d_ws;                       // 128 KB
    float* f1  = (float*)(WbT + 65536);              // 64 KB
    float* f2  = f1 + 16384;                         // 64 KB
    short* WhT = (short*)(f2 + 16384);               // 8 MB
    unsigned long long* bits =
        (unsigned long long*)(WhT + 16 * 256 * 1024);// 2 MB

    prep<<<64, 256, 0, stream>>>(W, WbT);
    setup2<<<4608, 256, 0, stream>>>(h, WbT, a, adj, WhT, f1, f2, bits);
    fused_agg<<<256, 512, 0, stream>>>(bits, f1, f2, WhT, out);
}